// Round 2
// baseline (178.002 us; speedup 1.0000x reference)
//
#include <hip/hip_runtime.h>

// 3x3 median blur + residual, zero padding, x:(8,3,1024,1024) f32.
// LDS-DMA streaming kernel: per block, a 16-row x 1024-px strip walked with a
// 6-slot LDS row ring filled by global_load_lds (no destination VGPR -> the
// compiler CANNOT collapse the prefetch distance; round-1 post-mortem showed
// VGPR=36 i.e. the register ring was serialized). The only vmcnt waits in the
// loop are hand-counted inline asm (T3/T4: counted, never drain-to-0): 3 DMA
// rows + 3 stores stay in flight across raw s_barriers. Halos read straight
// from LDS (no shfl, no extra global loads). Plain stores (round0/1 both
// plateaued at exactly 98MB/62us = 1.6 TB/s with nontemporal stores).
//
// vmem issue order per body i (pinned by asm memory clobbers):
//   DMA(k=i+5) ; WAIT ; BARRIER ; ds_reads ; compute ; STORE(i)
// Needed row k=i+2 was DMA'd at body(i-3); younger vmem entries at WAIT:
//   {S(i-3), D(i+3), S(i-2), D(i+4), S(i-1), D(i+5)} = 6 (steady state)
//   ramp-up/down: i=0:3, i=1:4, i=2:5, i=13:5, i=14:4, i=15:3.
// Ring safety: DMA(k) overwrites slot of row k-6, last ds_read 3 barriers
// earlier and consumed into regs (compiler lgkm wait before compute) before
// the following barrier -> no race.

typedef float v4f __attribute__((ext_vector_type(4)));

#define S2(a,b) { float _t=fminf(a,b); (b)=fmaxf(a,b); (a)=_t; }
__device__ __forceinline__ float med3f(float a, float b, float c) {
    return fmaxf(fminf(a, b), fminf(fmaxf(a, b), c));
}

constexpr int W  = 1024, H = 1024;
constexpr int RS = 16;            // output rows per block
constexpr int NS = 6;             // LDS ring slots (4 KB each)

typedef const __attribute__((address_space(1))) void gld_g;
typedef __attribute__((address_space(3))) void gld_s;

#define WAITV(n)  asm volatile("s_waitcnt vmcnt(" #n ")" ::: "memory")
#define BARRIER() asm volatile("s_barrier" ::: "memory")

__global__ __launch_bounds__(256, 6) void median_blur_kernel(
    const float* __restrict__ xin, float* __restrict__ out)
{
    __shared__ float ring[NS][W];                 // 24 KB -> 6 blocks/CU (144/160 KB)

    const int tx = threadIdx.x;
    const int x0 = tx << 2;                       // 4 px per thread, full row
    const int y0 = (int)blockIdx.x * RS;
    const size_t plane = (size_t)blockIdx.y * (size_t)(H * W);
    const float* base  = xin + plane;
    float*       obase = out + plane;

    const bool lE = (tx == 0), rE = (tx == 255);
    const int  xl = lE ? 0     : x0 - 1;          // clamped LDS halo col (value zeroed at use)
    const int  xr = rE ? W - 1 : x0 + 4;
    const bool topB = (blockIdx.x == 0);
    const bool botB = (blockIdx.x == (H / RS) - 1);

    // rolling 3-row register window; all indices compile-time after unroll
    float win[3][6];

    // DMA input row k (absolute y = y0-1+k, clamped) into ring[k%NS]
    auto DMA = [&](int k) {
        int y = y0 - 1 + k;
        y = y < 0 ? 0 : (y > H - 1 ? H - 1 : y);  // clamped addr; zeroed at compute
        const float* g = base + ((size_t)y << 10) + x0;
        __builtin_amdgcn_global_load_lds((gld_g*)g, (gld_s*)&ring[k % NS][x0], 16, 0, 0);
    };
    // read row k from LDS into win[k%3] (6-wide, image-edge cols zeroed)
    auto RD = [&](int k) {
        const int s = k % NS;
        v4f c = *reinterpret_cast<const v4f*>(&ring[s][x0]);
        float hl = ring[s][xl];
        float hr = ring[s][xr];
        float* w = win[k % 3];
        w[0] = lE ? 0.0f : hl;
        w[1] = c.x; w[2] = c.y; w[3] = c.z; w[4] = c.w;
        w[5] = rE ? 0.0f : hr;
    };

    // ---- prologue: rows k=0..4 in flight; k=0,1 landed and read
#pragma unroll
    for (int k = 0; k < 5; ++k) DMA(k);
    WAITV(3);                                     // D0,D1 done (younger: D2,D3,D4)
    BARRIER();
    RD(0); RD(1);
    if (topB) {                                   // input row -1 is zero padding
#pragma unroll
        for (int j = 0; j < 6; ++j) win[0][j] = 0.0f;
    }

    // ---- main march: body(i) computes output row y0+i
#pragma unroll
    for (int i = 0; i < RS; ++i) {
        if (i + 5 <= RS + 1) DMA(i + 5);          // rows k<=17 exist (i<=12)

        // counted wait: guarantee row k=i+2 landed (counts derived above)
        if      (i == 0)            WAITV(3);
        else if (i == 1)            WAITV(4);
        else if (i == 2 || i == 13) WAITV(5);
        else if (i == 14)           WAITV(4);
        else if (i == 15)           WAITV(3);
        else                        WAITV(6);

        BARRIER();                                // all waves' row i+2 visible

        RD(i + 2);
        if (i == RS - 1 && botB) {                // input row H is zero padding
#pragma unroll
            for (int j = 0; j < 6; ++j) win[(i + 2) % 3][j] = 0.0f;
        }

        const float* t = win[i % 3];
        const float* m = win[(i + 1) % 3];
        const float* b = win[(i + 2) % 3];

        float lo[6], mi[6], hi[6];
#pragma unroll
        for (int j = 0; j < 6; ++j) {
            float a = t[j], c0 = m[j], d = b[j];
            S2(a, c0); S2(c0, d); S2(a, c0);
            lo[j] = a; mi[j] = c0; hi[j] = d;
        }
        v4f o;
#pragma unroll
        for (int j = 0; j < 4; ++j) {
            const float mxlo = fmaxf(lo[j], fmaxf(lo[j + 1], lo[j + 2]));
            const float mnhi = fminf(hi[j], fminf(hi[j + 1], hi[j + 2]));
            const float mdmi = med3f(mi[j], mi[j + 1], mi[j + 2]);
            const float med  = med3f(mxlo, mdmi, mnhi);
            const float xc   = m[j + 1];
            o[j] = xc + 0.2f * (med - xc);
        }
        *reinterpret_cast<v4f*>(obase + ((size_t)(y0 + i) << 10) + x0) = o;
    }
}

extern "C" void kernel_launch(void* const* d_in, const int* in_sizes, int n_in,
                              void* d_out, int out_size, void* d_ws, size_t ws_size,
                              hipStream_t stream) {
    const float* x = (const float*)d_in[0];
    float* out = (float*)d_out;
    const int planes = in_sizes[0] / (H * W);     // 24
    dim3 block(256);
    dim3 grid(H / RS, planes);                    // 64 x 24 = 1536 blocks = 6/CU
    median_blur_kernel<<<grid, block, 0, stream>>>(x, out);
}

// Round 5
// 175.531 us; speedup vs baseline: 1.0141x; 1.0141x over previous
//
#include <hip/hip_runtime.h>

// 3x3 median blur + residual, zero padding, x:(8,3,1024,1024) f32.
// Round-3 experiment (2nd resubmit; R3+R4 benches were GPUAcquisitionTimeout,
// never ran). Deep per-wave MLP, physically enforced.
// R0/R1/R2 (reg-burst, reg-ring, LDS-DMA+counted-vmcnt) all ran identically
// (63us, 2.4 TB/s, VALUBusy 22%): waves memory-starved at ~4 B/cyc/CU.
// R1's ring was collapsed by the allocator (VGPR=36 -> no MLP). Here the
// loads are raw inline-asm global_load_dwordx4/dword: the compiler cannot
// sink them, cannot kill their live ranges, and adds NO implicit waitcnt.
// Hand-counted vmcnt(N) + sched_barrier(0) (rule #18) are the only waits:
// steady state keeps 9 loads + 3 stores in flight PER WAVE, no barriers,
// no LDS, no shfl -- waves fully independent.
//
// vmem queue (in-order) at body(i)'s WAIT, steady state (need grp(i+2),
// issued 3 bodies ago): S(i-3) grp(i+3) S(i-2) grp(i+4) S(i-1) grp(i+5)
//   = 3 stores + 9 loads = vmcnt(12). Ramp i=0,1,2: 9,10,11; drain
//   i=13,14,15: 9,6,3 (no issue for i>12).

typedef float v4f __attribute__((ext_vector_type(4)));
typedef unsigned long long u64;

#define S2(a,b) { float _t=fminf(a,b); (b)=fmaxf(a,b); (a)=_t; }
__device__ __forceinline__ float med3f(float a, float b, float c) {
    return fmaxf(fminf(a, b), fminf(fmaxf(a, b), c));
}

constexpr int W = 1024, H = 1024;
constexpr int RS = 16;            // output rows per block
constexpr int P  = 6;             // register ring rows (3 in flight + 3 live)

#define LOADX4(dst, p) asm volatile("global_load_dwordx4 %0, %1, off" \
    : "=&v"(dst) : "v"((u64)(p)) : "memory")
#define LOADD(dst, p)  asm volatile("global_load_dword %0, %1, off" \
    : "=&v"(dst) : "v"((u64)(p)) : "memory")
#define WAITV(n) do { asm volatile("s_waitcnt vmcnt(" #n ")" ::: "memory"); \
    __builtin_amdgcn_sched_barrier(0); } while (0)

__global__ __launch_bounds__(256, 6) void median_blur_kernel(
    const float* __restrict__ xin, float* __restrict__ out)
{
    const int tx = threadIdx.x;
    const int x0 = tx << 2;                       // 4 px per thread, full row
    const int y0 = (int)blockIdx.x * RS;
    const size_t plane = (size_t)blockIdx.y * (size_t)(H * W);
    const float* base  = xin + plane;
    float*       obase = out + plane;

    const bool lE = (tx == 0), rE = (tx == 255);
    const int  xl = lE ? x0     : x0 - 1;         // clamped halo addr (zeroed at use)
    const int  xr = rE ? x0 + 3 : x0 + 4;
    const bool topB = (blockIdx.x == 0);
    const bool botB = (blockIdx.x == gridDim.x - 1);

    v4f   cc[P];                                  // ring: center 4 px
    float ll[P], rr[P];                           // ring: halo px

    // issue load group for ring row k (input y = y0-1+k, clamped; pad zeroed at use)
#define ISSUE(k) do {                                                     \
        int _y = y0 - 1 + (k);                                            \
        _y = _y < 0 ? 0 : (_y > H - 1 ? H - 1 : _y);                      \
        const float* _rp = base + ((size_t)_y << 10);                     \
        LOADX4(cc[(k) % P], _rp + x0);                                    \
        LOADD(ll[(k) % P], _rp + xl);                                     \
        LOADD(rr[(k) % P], _rp + xr);                                     \
    } while (0)

    // ---- prologue: 5 row-groups in flight (15 loads), zero waits
    ISSUE(0); ISSUE(1); ISSUE(2); ISSUE(3); ISSUE(4);

    // ---- main march: body(i) computes output row y0+i from rows i,i+1,i+2
#pragma unroll
    for (int i = 0; i < RS; ++i) {
        if (i <= RS - 4) ISSUE(i + 5);            // rows k = 5..17

        if      (i == 0)  WAITV(9);
        else if (i == 1)  WAITV(10);
        else if (i == 2)  WAITV(11);
        else if (i == 13) WAITV(9);
        else if (i == 14) WAITV(6);
        else if (i == 15) WAITV(3);
        else              WAITV(12);

        const int sT = i % P, sM = (i + 1) % P, sB = (i + 2) % P;

        float t[6] = { lE ? 0.0f : ll[sT], cc[sT].x, cc[sT].y, cc[sT].z, cc[sT].w, rE ? 0.0f : rr[sT] };
        float m[6] = { lE ? 0.0f : ll[sM], cc[sM].x, cc[sM].y, cc[sM].z, cc[sM].w, rE ? 0.0f : rr[sM] };
        float b[6] = { lE ? 0.0f : ll[sB], cc[sB].x, cc[sB].y, cc[sB].z, cc[sB].w, rE ? 0.0f : rr[sB] };

        if (i == 0) {                             // input row -1 is zero padding
            if (topB) {
#pragma unroll
                for (int j = 0; j < 6; ++j) t[j] = 0.0f;
            }
        }
        if (i == RS - 1) {                        // input row H is zero padding
            if (botB) {
#pragma unroll
                for (int j = 0; j < 6; ++j) b[j] = 0.0f;
            }
        }

        // vertical sort3 per column, then med3-of-candidates per output px
        float lo[6], mi[6], hi[6];
#pragma unroll
        for (int j = 0; j < 6; ++j) {
            float a = t[j], c0 = m[j], d = b[j];
            S2(a, c0); S2(c0, d); S2(a, c0);
            lo[j] = a; mi[j] = c0; hi[j] = d;
        }
        v4f o;
#pragma unroll
        for (int j = 0; j < 4; ++j) {
            const float mxlo = fmaxf(lo[j], fmaxf(lo[j + 1], lo[j + 2]));
            const float mnhi = fminf(hi[j], fminf(hi[j + 1], hi[j + 2]));
            const float mdmi = med3f(mi[j], mi[j + 1], mi[j + 2]);
            const float med  = med3f(mxlo, mdmi, mnhi);
            const float xc   = m[j + 1];
            o[j] = xc + 0.2f * (med - xc);
        }
        *reinterpret_cast<v4f*>(obase + ((size_t)(y0 + i) << 10) + x0) = o;
    }
#undef ISSUE
}

extern "C" void kernel_launch(void* const* d_in, const int* in_sizes, int n_in,
                              void* d_out, int out_size, void* d_ws, size_t ws_size,
                              hipStream_t stream) {
    const float* x = (const float*)d_in[0];
    float* out = (float*)d_out;
    const int planes = in_sizes[0] / (H * W);     // 24
    dim3 block(256);
    dim3 grid(H / RS, planes);                    // 64 x 24 = 1536 blocks = 6/CU
    median_blur_kernel<<<grid, block, 0, stream>>>(x, out);
}